// Round 15
// baseline (2177.229 us; speedup 1.0000x reference)
//
#include <hip/hip_runtime.h>
#include <hip/hip_bf16.h>
#include <math.h>
#include <stdint.h>

typedef unsigned int u32;
typedef unsigned short u16;
typedef unsigned long long u64;

#define NM   65536
#define HD   1024
#define KS   128
#define SQ   258
#define NL   4
#define NBIN 65536
#define CCAP 2048

using bf16x8 = __attribute__((ext_vector_type(8))) short;
using f32x4v = __attribute__((ext_vector_type(4))) float;

static constexpr size_t A256(size_t x){ return (x + 255) & ~(size_t)255; }

// ---- zeroed region (folded into k_wconv): hist3 + cnt3 + histS + tile counters ----
constexpr size_t OFF_H3   = 0;
constexpr size_t OFF_C3   = OFF_H3 + (size_t)3*NBIN*4;
constexpr size_t OFF_HS   = OFF_C3 + (size_t)3*NBIN*4;
constexpr size_t OFF_CTR  = OFF_HS + (size_t)NBIN*4;            // 4096 u32 (per-layer: qkv 240 @ l*1024, ffn1 320 @ l*1024+512)
constexpr size_t ZERO_BYTES = OFF_CTR + 16384;                  // 1808 KB
constexpr u32 ZBLK = 1808;
// ---- rest ----
constexpr size_t OFF_BS   = A256(ZERO_BYTES);
constexpr size_t OFF_P3   = A256(OFF_BS + 192*4);
constexpr size_t OFF_K3   = A256(OFF_P3 + (size_t)3*(NBIN+1)*4);
constexpr size_t OFF_L3   = A256(OFF_K3 + (size_t)3*NM*4);            // u16 lo3
constexpr size_t OFF_KSC  = A256(OFF_L3 + (size_t)3*NM*2);
constexpr size_t OFF_IDX  = A256(OFF_KSC + (size_t)NM*4);
constexpr size_t OFF_REW  = A256(OFF_IDX  + (size_t)KS*4);
constexpr size_t OFF_HM   = A256(OFF_REW  + (size_t)KS*4);
constexpr size_t OFF_HT   = A256(OFF_HM   + (size_t)KS*HD*2);
constexpr size_t OFF_VECS = A256(OFF_HT   + (size_t)KS*HD*2);
constexpr size_t OFF_LNB  = A256(OFF_VECS + (size_t)SQ*HD*4);
constexpr size_t OFF_QKV  = A256(OFF_LNB  + (size_t)SQ*HD*2);
constexpr size_t OFF_ATT  = A256(OFF_QKV  + (size_t)SQ*3*HD*2);
constexpr size_t OFF_FFH  = A256(OFF_ATT  + (size_t)SQ*HD*2);
constexpr size_t OFF_VHIN = A256(OFF_FFH  + (size_t)SQ*4*HD*2);
constexpr size_t OFF_WB   = A256(OFF_VHIN + (size_t)129*HD*2);
constexpr size_t NWELEM   = 56623104;
constexpr size_t OFF_PART = A256(OFF_WB + NWELEM*2);

constexpr size_t WB_IN = 0;
constexpr size_t WB_O  = WB_IN + (size_t)4*3*HD*HD;
constexpr size_t WB_F1 = WB_O  + (size_t)4*HD*HD;
constexpr size_t WB_F2 = WB_F1 + (size_t)4*4*HD*HD;
constexpr size_t WB_AM = WB_F2 + (size_t)4*4*HD*HD;
constexpr size_t WB_AT = WB_AM + (size_t)HD*HD;
constexpr size_t WB_VH = WB_AT + (size_t)HD*HD;

// output layout (floats)
constexpr int OUT_NEXT = 257*HD;
constexpr int OUT_VP   = OUT_NEXT + KS*HD;
constexpr int OUT_LOSS = OUT_VP + 1;
constexpr int OUT_REWO = OUT_LOSS + KS;

__device__ __forceinline__ float gelu_f(float v){
  return 0.5f*v*(1.0f + erff(v*0.70710678118654752440f));
}

__device__ __forceinline__ u16 f2bf(float f){
  __hip_bfloat16 h = __float2bfloat16(f);
  u16 s; __builtin_memcpy(&s, &h, sizeof(u16));
  return s;
}

__device__ __forceinline__ float bf2f(u16 v){ return __uint_as_float(((u32)v) << 16); }

__device__ __forceinline__ float4 unpk4(u64 pk){
  u32 lo = (u32)pk, hi = (u32)(pk >> 32);
  float4 v;
  v.x = __uint_as_float(lo << 16);
  v.y = __uint_as_float(lo & 0xFFFF0000u);
  v.z = __uint_as_float(hi << 16);
  v.w = __uint_as_float(hi & 0xFFFF0000u);
  return v;
}

__device__ __forceinline__ u64 pk4(float4 v){
  u16 r[4] = { f2bf(v.x), f2bf(v.y), f2bf(v.z), f2bf(v.w) };
  u64 pk; __builtin_memcpy(&pk, r, 8);
  return pk;
}

__device__ __forceinline__ u32 fkey(float v){
  u32 b = __float_as_uint(v);
  return (b >> 31) ? ~b : (b | 0x80000000u);
}

__device__ __forceinline__ void gload16(const u16* g, u16* l){
  __builtin_amdgcn_global_load_lds(
      (const __attribute__((address_space(1))) unsigned int*)g,
      (__attribute__((address_space(3))) unsigned int*)l, 16, 0, 0);
}

// ----------------- weight conversion fp32 -> bf16 (+ zero hist/counter regions) -----------------
struct WSeg { const float* s; u16* d; u32 base4, end4; };
struct WCA { WSeg seg[7]; u32 tot4; u32* z; };
__global__ __launch_bounds__(256) void k_wconv(WCA a){
  if(blockIdx.x < ZBLK) a.z[blockIdx.x*256 + threadIdx.x] = 0u;
  u32 i = blockIdx.x*256 + threadIdx.x;
  if(i >= a.tot4) return;
  #pragma unroll
  for(int j=0;j<7;++j){
    if(i < a.seg[j].end4){
      u32 off = i - a.seg[j].base4;
      float4 v = *(const float4*)&a.seg[j].s[(size_t)off*4];
      *(u64*)&a.seg[j].d[(size_t)off*4] = pk4(v);
      return;
    }
  }
}

// ----------------- fused xnorm + sim + keys + hist (8 rows/block) -----------------
__global__ __launch_bounds__(256) void k_simkey(const float* __restrict__ mv, const float* __restrict__ x,
                                                const float* __restrict__ surp, const float* __restrict__ noise,
                                                u32* __restrict__ keys3, u32* __restrict__ hist3){
  __shared__ float xs[HD];
  __shared__ float red[256];
  int t = threadIdx.x;
  float s = 0.f;
  for(int i=t;i<HD;i+=256){ float v=x[i]; s += v*v; }
  red[t]=s; __syncthreads();
  for(int o=128;o>0;o>>=1){ if(t<o) red[t]+=red[t+o]; __syncthreads(); }
  float nrm = fmaxf(sqrtf(red[0]), 1e-8f);
  for(int i=t;i<HD;i+=256) xs[i] = x[i]/nrm;
  __syncthreads();
  int lane = t & 63, w = t >> 6;
  #pragma unroll
  for(int rep=0;rep<2;++rep){
    int row = blockIdx.x*8 + rep*4 + w;
    const float4* p = (const float4*)(mv + (size_t)row*HD);
    const float4* q = (const float4*)xs;
    float d=0.f, ss=0.f;
    #pragma unroll
    for(int r=0;r<4;++r){
      float4 v = p[lane + 64*r]; float4 u = q[lane + 64*r];
      d  += v.x*u.x + v.y*u.y + v.z*u.z + v.w*u.w;
      ss += v.x*v.x + v.y*v.y + v.z*v.z + v.w*v.w;
    }
    for(int off=32;off>0;off>>=1){ d += __shfl_xor(d,off,64); ss += __shfl_xor(ss,off,64); }
    if(lane==0){
      float sim = d / fmaxf(sqrtf(ss),1e-8f);
      float vals[3] = { surp[row], sim, noise[row] };
      #pragma unroll
      for(int a=0;a<3;++a){
        u32 k = fkey(vals[a]);
        keys3[(size_t)a*NM + row] = k;
        atomicAdd(&hist3[(size_t)a*NBIN + (k >> 16)], 1u);
      }
    }
  }
}

// ----------------- scan -----------------
__global__ __launch_bounds__(256) void k_scanA(const u32* __restrict__ hist3, u32* __restrict__ bsum){
  __shared__ u32 red[256];
  int blk = blockIdx.x;
  int t = threadIdx.x;
  const u32* h = hist3 + (size_t)(blk>>6)*NBIN + (size_t)(blk&63)*1024;
  u32 s = 0;
  #pragma unroll
  for(int j=0;j<4;++j) s += h[t*4+j];
  red[t]=s; __syncthreads();
  for(int o=128;o>0;o>>=1){ if(t<o) red[t]+=red[t+o]; __syncthreads(); }
  if(t==0) bsum[blk] = red[0];
}

__global__ __launch_bounds__(256) void k_scanC(const u32* __restrict__ hist3, const u32* __restrict__ bsum,
                                               u32* __restrict__ pref3){
  __shared__ u32 part[256];
  int blk = blockIdx.x;
  int t = threadIdx.x;
  int a = blk >> 6, c = blk & 63;
  u32 base = 0;
  for(int j=0;j<c;++j) base += bsum[a*64 + j];
  const u32* h = hist3 + (size_t)a*NBIN + (size_t)c*1024;
  u32* pref = pref3 + (size_t)a*(NBIN+1) + (size_t)c*1024;
  u32 loc[4]; u32 s = 0;
  #pragma unroll
  for(int j=0;j<4;++j){ loc[j] = h[t*4+j]; s += loc[j]; }
  part[t] = s; __syncthreads();
  for(int off=1;off<256;off<<=1){
    u32 u = (t >= off) ? part[t-off] : 0u;
    __syncthreads(); part[t] += u; __syncthreads();
  }
  u32 run = base + part[t] - s;
  #pragma unroll
  for(int j=0;j<4;++j){ pref[t*4+j] = run; run += loc[j]; }
  if(c == 63 && t == 255) pref3[(size_t)a*(NBIN+1) + NBIN] = NM;
}

// ----------------- scatter / rank+score -----------------
__global__ void k_scatter3(const u32* __restrict__ keys3, const u32* __restrict__ pref3,
                           u32* __restrict__ cnt3, u16* __restrict__ lo3){
  int i = blockIdx.x*256 + threadIdx.x;
  if(i >= NM) return;
  #pragma unroll
  for(int a=0;a<3;++a){
    u32 k = keys3[(size_t)a*NM + i];
    u32 b = k >> 16;
    u32 pos = pref3[(size_t)a*(NBIN+1) + b] + atomicAdd(&cnt3[(size_t)a*NBIN + b], 1u);
    lo3[(size_t)a*NM + pos] = (u16)(k & 0xFFFFu);
  }
}

__global__ void k_rank3score(const u32* __restrict__ keys3, const u32* __restrict__ pref3,
                             const u16* __restrict__ lo3, u32* __restrict__ keysS, u32* __restrict__ histS){
  int i = blockIdx.x*256 + threadIdx.x;
  if(i >= NM) return;
  float rr[3];
  #pragma unroll
  for(int a=0;a<3;++a){
    u32 k = keys3[(size_t)a*NM + i];
    u32 b = k >> 16, my = k & 0xFFFFu;
    const u32* pref = pref3 + (size_t)a*(NBIN+1);
    const u16* lo = lo3 + (size_t)a*NM;
    u32 s = pref[b], e = pref[b+1];
    u32 nl = 0, ne = 0;
    for(u32 j=s;j<e;++j){ u32 u = lo[j]; nl += (u < my); ne += (u == my); }
    u32 left = s + nl, right = left + ne;
    rr[a] = (float)(left + right - 1) * (1.0f/131072.0f);
  }
  float sc = __fadd_rn(__fadd_rn(__fmul_rn(rr[0],rr[0]), __fmul_rn(rr[1],rr[1])), __fmul_rn(rr[2],rr[2]));
  u32 k = __float_as_uint(sc);
  keysS[i] = k;
  atomicAdd(&histS[k >> 16], 1u);
}

// ----------------- fused threshold + collect + bitonic sort -----------------
__global__ __launch_bounds__(1024) void k_selsort(const u32* __restrict__ histS, const u32* __restrict__ keysS,
                                                  int* __restrict__ idx){
  __shared__ u32 part[1024];
  __shared__ u64 sm[CCAP];
  __shared__ u32 thrT, cnt;
  int t = threadIdx.x;
  u32 base = t*64, s = 0;
  for(int j=0;j<64;++j) s += histS[base+j];
  part[t] = s; __syncthreads();
  for(int off=1;off<1024;off<<=1){
    u32 v = (t+off < 1024) ? part[t+off] : 0u;
    __syncthreads(); part[t] += v; __syncthreads();
  }
  u32 above = part[t] - s;
  if(above < (u32)KS && above + s >= (u32)KS){
    u32 cum = above;
    for(int j=63;j>=0;--j){
      u32 c = histS[base+j];
      if(cum + c >= (u32)KS){ thrT = (u32)(base+j) << 16; cnt = 0; break; }
      cum += c;
    }
  }
  __syncthreads();
  u32 T = thrT;
  for(int i=t;i<NM;i+=1024){
    u32 k = keysS[i];
    if(k >= T){
      u32 p = atomicAdd(&cnt, 1u);
      if(p < (u32)CCAP) sm[p] = ((u64)(~k) << 32) | (u32)i;
    }
  }
  __syncthreads();
  u32 n = cnt; if(n > (u32)CCAP) n = CCAP;
  for(int i=t;i<CCAP;i+=1024) if(i >= (int)n) sm[i] = 0xFFFFFFFFFFFFFFFFull;
  __syncthreads();
  for(int k=2;k<=CCAP;k<<=1){
    for(int j=k>>1;j>0;j>>=1){
      for(int i=t;i<CCAP;i+=1024){
        int ixj = i ^ j;
        if(ixj > i){
          bool up = ((i & k) == 0);
          u64 a = sm[i], b = sm[ixj];
          if((a > b) == up){ sm[i] = b; sm[ixj] = a; }
        }
      }
      __syncthreads();
    }
  }
  if(t < KS) idx[t] = (int)(sm[t] & 0xFFFFFFFFu);
}

// ----------------- gather -----------------
__global__ void k_gather(const int* __restrict__ idx,
                         const float* __restrict__ mv, const float* __restrict__ mnv,
                         const float* __restrict__ mrew,
                         const int* __restrict__ aim, const int* __restrict__ ait,
                         const float* __restrict__ amw1, const float* __restrict__ amb1,
                         const float* __restrict__ atw1, const float* __restrict__ atb1,
                         const float* __restrict__ start, const float* __restrict__ x,
                         const float* __restrict__ pos,
                         float* __restrict__ vecs, float* __restrict__ outnext,
                         u16* __restrict__ hm, u16* __restrict__ ht,
                         float* __restrict__ rew, float* __restrict__ outrew){
  int k = blockIdx.x;
  int t = threadIdx.x;
  if(k < KS){
    int row = idx[k];
    const float4* a = (const float4*)(mv  + (size_t)row*HD);
    const float4* b = (const float4*)(mnv + (size_t)row*HD);
    const float4* pz = (const float4*)(pos + (size_t)(2*k+1)*HD);
    float4* vr = (float4*)(vecs + (size_t)(2*k+1)*HD);
    float4* on = (float4*)(outnext + (size_t)k*HD);
    float4 av = a[t], bv = b[t], pv = pz[t];
    av.x += pv.x; av.y += pv.y; av.z += pv.z; av.w += pv.w;
    vr[t] = av; on[t] = bv;
    int am = aim[row], at = ait[row];
    for(int j=t;j<HD;j+=256){
      hm[(size_t)k*HD+j] = f2bf(gelu_f(amw1[(size_t)j*9 + am] + amb1[j]));
      ht[(size_t)k*HD+j] = f2bf(gelu_f(atw1[(size_t)j*4 + at] + atb1[j]));
    }
    if(t == 0){ float r = mrew[row]; rew[k] = r; outrew[k] = r; }
  } else {
    const float4* st = (const float4*)start;
    const float4* xx = (const float4*)x;
    const float4* p0 = (const float4*)pos;
    const float4* p1 = (const float4*)(pos + (size_t)(SQ-1)*HD);
    float4 v0 = st[t], v1 = xx[t], q0 = p0[t], q1 = p1[t];
    v0.x += q0.x; v0.y += q0.y; v0.z += q0.z; v0.w += q0.w;
    v1.x += q1.x; v1.y += q1.y; v1.z += q1.z; v1.w += q1.w;
    ((float4*)vecs)[t] = v0;
    ((float4*)(vecs + (size_t)(SQ-1)*HD))[t] = v1;
  }
}

// ----------------- bf16 MFMA split-K GEMM, BK=64 (global_load_lds, dbuf) -> bf16 partials -----------------
__device__ __forceinline__ void gemm_body(u16* As, u16* Bs, const u16* __restrict__ A, const u16* __restrict__ B,
        u16* __restrict__ P, int M, int N, int K, int S, int nbm, int lda, int tile){
  int bm = (tile % nbm) * 64;
  int tmp = tile / nbm;
  int z  = tmp % S;
  int bn = (tmp / S) * 64;
  int Ks = K / S, kbeg = z*Ks;
  int nk = Ks >> 6;

  int t = threadIdx.x, lane = t & 63, w = t >> 6;
  int s0 = w*64 + lane, s1 = s0 + 256;
  int r0s = s0 >> 3, c0s = (s0 & 7) ^ (r0s & 7);
  int r1s = s1 >> 3, c1s = (s1 & 7) ^ (r1s & 7);
  const u16* ga0 = A + (size_t)(bm + r0s)*lda + kbeg + c0s*8;
  const u16* ga1 = A + (size_t)(bm + r1s)*lda + kbeg + c1s*8;
  const u16* gb0 = B + (size_t)(bn + r0s)*K  + kbeg + c0s*8;
  const u16* gb1 = B + (size_t)(bn + r1s)*K  + kbeg + c1s*8;
  int lb0 = w*512, lb1 = 2048 + w*512;

  int wm = (w >> 1)*32, wn = (w & 1)*32;
  int lr = lane & 15, lg = lane >> 4;
  int ra0 = wm + lr, ra1 = ra0 + 16;
  int rb0 = wn + lr, rb1 = rb0 + 16;
  int a00 = ra0*64 + ((lg     ^ (ra0&7))*8);
  int a01 = ra0*64 + (((4+lg) ^ (ra0&7))*8);
  int a10 = ra1*64 + ((lg     ^ (ra1&7))*8);
  int a11 = ra1*64 + (((4+lg) ^ (ra1&7))*8);
  int b00 = rb0*64 + ((lg     ^ (rb0&7))*8);
  int b01 = rb0*64 + (((4+lg) ^ (rb0&7))*8);
  int b10 = rb1*64 + ((lg     ^ (rb1&7))*8);
  int b11 = rb1*64 + (((4+lg) ^ (rb1&7))*8);

  f32x4v acc00 = {0,0,0,0}, acc01 = {0,0,0,0}, acc10 = {0,0,0,0}, acc11 = {0,0,0,0};

  gload16(ga0, As + lb0); gload16(ga1, As + lb1);
  gload16(gb0, Bs + lb0); gload16(gb1, Bs + lb1);
  ga0 += 64; ga1 += 64; gb0 += 64; gb1 += 64;
  __syncthreads();

  for(int kk = 0; kk < nk; ++kk){
    int cur = (kk & 1) << 12;
    if(kk + 1 < nk){
      int nxt = cur ^ 4096;
      gload16(ga0, As + nxt + lb0); gload16(ga1, As + nxt + lb1);
      gload16(gb0, Bs + nxt + lb0); gload16(gb1, Bs + nxt + lb1);
      ga0 += 64; ga1 += 64; gb0 += 64; gb1 += 64;
    }
    bf16x8 xa0 = *(const bf16x8*)&As[cur + a00];
    bf16x8 xa1 = *(const bf16x8*)&As[cur + a10];
    bf16x8 xb0 = *(const bf16x8*)&Bs[cur + b00];
    bf16x8 xb1 = *(const bf16x8*)&Bs[cur + b10];
    acc00 = __builtin_amdgcn_mfma_f32_16x16x32_bf16(xa0, xb0, acc00, 0, 0, 0);
    acc01 = __builtin_amdgcn_mfma_f32_16x16x32_bf16(xa0, xb1, acc01, 0, 0, 0);
    acc10 = __builtin_amdgcn_mfma_f32_16x16x32_bf16(xa1, xb0, acc10, 0, 0, 0);
    acc11 = __builtin_amdgcn_mfma_f32_16x16x32_bf16(xa1, xb1, acc11, 0, 0, 0);
    xa0 = *(const bf16x8*)&As[cur + a01];
    xa1 = *(const bf16x8*)&As[cur + a11];
    xb0 = *(const bf16x8*)&Bs[cur + b01];
    xb1 = *(const bf16x8*)&Bs[cur + b11];
    acc00 = __builtin_amdgcn_mfma_f32_16x16x32_bf16(xa0, xb0, acc00, 0, 0, 0);
    acc01 = __builtin_amdgcn_mfma_f32_16x16x32_bf16(xa0, xb1, acc01, 0, 0, 0);
    acc10 = __builtin_amdgcn_mfma_f32_16x16x32_bf16(xa1, xb0, acc10, 0, 0, 0);
    acc11 = __builtin_amdgcn_mfma_f32_16x16x32_bf16(xa1, xb1, acc11, 0, 0, 0);
    __syncthreads();
  }

  size_t zbase = (size_t)z * (size_t)M;
  #pragma unroll
  for(int r=0;r<4;++r){
    int row0 = bm + wm + lg*4 + r;
    int row1 = row0 + 16;
    int cc0 = bn + wn + lr, cc1 = cc0 + 16;
    if(row0 < M){
      P[(zbase+row0)*N + cc0] = f2bf(acc00[r]);
      P[(zbase+row0)*N + cc1] = f2bf(acc01[r]);
    }
    if(row1 < M){
      P[(zbase+row1)*N + cc0] = f2bf(acc10[r]);
      P[(zbase+row1)*N + cc1] = f2bf(acc11[r]);
    }
  }
}

__global__ __launch_bounds__(256) void k_gemm(const u16* __restrict__ A, const u16* __restrict__ B,
        u16* __restrict__ P, int M, int N, int K, int S, int nbm, int lda){
  __shared__ u16 As[8192];
  __shared__ u16 Bs[8192];
  u32 nwg = gridDim.x, orig = blockIdx.x;
  u32 swz = (orig & 7)*(nwg >> 3) + (orig >> 3);
  gemm_body(As, Bs, A, B, P, M, N, K, S, nbm, lda, (int)swz);
}

// self-finalizing variant: last block per (bm,bn) tile sums S slices + bias (+gelu) -> Cb
template<int S_, int ACT>
__global__ __launch_bounds__(256) void k_gemmF(const u16* __restrict__ A, const u16* __restrict__ B,
        u16* __restrict__ P, const float* __restrict__ bias, u16* __restrict__ Cb,
        u32* __restrict__ ctr, int M, int N, int K, int nbm, int lda){
  __shared__ u16 As[8192];
  __shared__ u16 Bs[8192];
  __shared__ u32 lastflag;
  u32 nwg = gridDim.x, orig = blockIdx.x;
  u32 swz = (orig & 7)*(nwg >> 3) + (orig >> 3);
  gemm_body(As, Bs, A, B, P, M, N, K, S_, nbm, lda, (int)swz);
  int tile = (int)swz;
  int bmi = tile % nbm;
  int tmp = tile / nbm;
  int bni = tmp / S_;
  int nbn = N >> 6;
  __threadfence();
  __syncthreads();
  if(threadIdx.x == 0){
    u32 old = atomicAdd(&ctr[bmi*nbn + bni], 1u);
    lastflag = (old == (u32)(S_-1)) ? 1u : 0u;
  }
  __syncthreads();
  if(lastflag){
    __threadfence();
    int bm = bmi*64, bn = bni*64;
    for(int idx = threadIdx.x; idx < 1024; idx += 256){
      int rl = idx >> 4, cg = idx & 15;
      int row = bm + rl;
      if(row >= M) continue;
      int col = bn + cg*4;
      float4 v = unpk4(*(const u64*)&P[(size_t)row*N + col]);
      #pragma unroll
      for(int z=1; z<S_; ++z){
        float4 q = unpk4(*(const u64*)&P[((size_t)z*M + row)*N + col]);
        v.x += q.x; v.y += q.y; v.z += q.z; v.w += q.w;
      }
      float4 b4 = *(const float4*)&bias[col];
      v.x += b4.x; v.y += b4.y; v.z += b4.z; v.w += b4.w;
      if(ACT == 1){ v.x = gelu_f(v.x); v.y = gelu_f(v.y); v.z = gelu_f(v.z); v.w = gelu_f(v.w); }
      *(u64*)&Cb[(size_t)row*N + col] = pk4(v);
    }
  }
}

__global__ __launch_bounds__(256) void k_actgemm(const u16* __restrict__ hm, const u16* __restrict__ ht,
        const u16* __restrict__ amw2, const u16* __restrict__ atw2,
        u16* __restrict__ part, u16* __restrict__ part2){
  __shared__ u16 As[8192];
  __shared__ u16 Bs[8192];
  int which = blockIdx.x >> 8, tile = blockIdx.x & 255;
  gemm_body(As, Bs, which ? ht : hm, which ? atw2 : amw2, which ? part2 : part,
            KS, HD, HD, 8, 2, HD, tile);
}

// ----------------- row finish: sum S_ bf16 slices + bias + residual; LN | copy-out -----------------
template<int S_, bool LN>
__global__ __launch_bounds__(256) void k_finrow(const u16* __restrict__ P, const float* __restrict__ bias,
                                                float* __restrict__ vecs, const float* __restrict__ lw,
                                                const float* __restrict__ lb, u16* __restrict__ lnb,
                                                float* __restrict__ outp, u16* __restrict__ vhin){
  __shared__ float red[256];
  int row = blockIdx.x, t = threadIdx.x;
  int j = t*4;
  float4 v = unpk4(*(const u64*)&P[(size_t)row*HD + j]);
  #pragma unroll
  for(int z=1;z<S_;++z){
    float4 p = unpk4(*(const u64*)&P[((size_t)z*SQ + row)*HD + j]);
    v.x += p.x; v.y += p.y; v.z += p.z; v.w += p.w;
  }
  float4 b4 = *(const float4*)&bias[j];
  float4 r4 = *(const float4*)&vecs[(size_t)row*HD + j];
  v.x += b4.x + r4.x; v.y += b4.y + r4.y; v.z += b4.z + r4.z; v.w += b4.w + r4.w;
  *(float4*)&vecs[(size_t)row*HD + j] = v;
  if(LN){
    red[t] = v.x+v.y+v.z+v.w; __syncthreads();
    for(int o=128;o>0;o>>=1){ if(t<o) red[t]+=red[t+o]; __syncthreads(); }
    float m = red[0]*(1.0f/HD); __syncthreads();
    float dx=v.x-m, dy=v.y-m, dz=v.z-m, dw=v.w-m;
    red[t] = dx*dx+dy*dy+dz*dz+dw*dw; __syncthreads();
    for(int o=128;o>0;o>>=1){ if(t<o) red[t]+=red[t+o]; __syncthreads(); }
    float den = sqrtf(red[0]*(1.0f/HD) + 1e-5f);
    float4 w4 = *(const float4*)&lw[j];
    float4 lb4 = *(const float4*)&lb[j];
    float4 o4;
    o4.x = dx/den*w4.x + lb4.x; o4.y = dy/den*w4.y + lb4.y;
    o4.z = dz/den*w4.z + lb4.z; o4.w = dw/den*w4.w + lb4.w;
    *(u64*)&lnb[(size_t)row*HD + j] = pk4(o4);
  } else {
    if(row >= 1) *(float4*)&outp[(size_t)(row-1)*HD + j] = v;
    if(row & 1){
      int vr = (row-1) >> 1;
      *(u64*)&vhin[(size_t)vr*HD + j] = pk4(v);
    }
  }
}

// ----------------- finav + LN1 -----------------
__global__ __launch_bounds__(256) void k_finavln(const u16* __restrict__ Pm, const u16* __restrict__ Pt,
                                                 const float* __restrict__ bm_, const float* __restrict__ bt_,
                                                 const float* __restrict__ pos, float* __restrict__ vecs,
                                                 const float* __restrict__ lw, const float* __restrict__ lb,
                                                 u16* __restrict__ lnb){
  __shared__ float red[256];
  int row = blockIdx.x, t = threadIdx.x;
  int j = t*4;
  float4 v;
  if(row >= 2 && row <= 256 && ((row & 1) == 0)){
    int k = (row-2) >> 1;
    float4 s = {0,0,0,0};
    #pragma unroll
    for(int z=0;z<8;++z){
      float4 a = unpk4(*(const u64*)&Pm[((size_t)z*KS + k)*HD + j]);
      float4 b = unpk4(*(const u64*)&Pt[((size_t)z*KS + k)*HD + j]);
      s.x += a.x+b.x; s.y += a.y+b.y; s.z += a.z+b.z; s.w += a.w+b.w;
    }
    float4 bm4 = *(const float4*)&bm_[j];
    float4 bt4 = *(const float4*)&bt_[j];
    float4 p4 = *(const float4*)&pos[(size_t)row*HD + j];
    v.x = 0.5f*(s.x + bm4.x + bt4.x) + p4.x;
    v.y = 0.5f*(s.y + bm4.y + bt4.y) + p4.y;
    v.z = 0.5f*(s.z + bm4.z + bt4.z) + p4.z;
    v.w = 0.5f*(s.w + bm4.w + bt4.w) + p4.w;
    *(float4*)&vecs[(size_t)row*HD + j] = v;
  } else {
    v = *(const float4*)&vecs[(size_t)row*HD + j];
  }
  red[t] = v.x+v.y+v.z+v.w; __syncthreads();
  for(int o=128;o>0;o>>=1){ if(t<o) red[t]+=red[t+o]; __syncthreads(); }
  float m = red[0]*(1.0f/HD); __syncthreads();
  float dx=v.x-m, dy=v.y-m, dz=v.z-m, dw=v.w-m;
  red[t] = dx*dx+dy*dy+dz*dz+dw*dw; __syncthreads();
  for(int o=128;o>0;o>>=1){ if(t<o) red[t]+=red[t+o]; __syncthreads(); }
  float den = sqrtf(red[0]*(1.0f/HD) + 1e-5f);
  float4 w4 = *(const float4*)&lw[j];
  float4 lb4 = *(const float4*)&lb[j];
  float4 o4;
  o4.x = dx/den*w4.x + lb4.x; o4.y = dy/den*w4.y + lb4.y;
  o4.z = dz/den*w4.z + lb4.z; o4.w = dw/den*w4.w + lb4.w;
  *(u64*)&lnb[(size_t)row*HD + j] = pk4(o4);
}

// ----------------- attention (paired q for load balance; bf16 in/out) -----------------
__global__ void k_attn(const u16* __restrict__ qkv, u16* __restrict__ outp){
  __shared__ float qv[64];
  __shared__ float p[SQ];
  __shared__ float red[256];
  int h = blockIdx.y, t = threadIdx.x;
  #pragma unroll
  for(int half=0; half<2; ++half){
    int q = half ? (SQ-1 - (int)blockIdx.x) : (int)blockIdx.x;
    if(t < 64) qv[t] = bf2f(qkv[(size_t)q*3072 + h*64 + t]);
    __syncthreads();
    int nk = q + 1;
    float lmax = -1e30f;
    for(int j=t;j<nk;j+=256){
      const u32* kr = (const u32*)(qkv + (size_t)j*3072 + 1024 + h*64);
      float d = 0.f;
      #pragma unroll
      for(int c2=0;c2<32;++c2){
        u32 pk = kr[c2];
        d += qv[c2*2]   * __uint_as_float(pk << 16);
        d += qv[c2*2+1] * __uint_as_float(pk & 0xFFFF0000u);
      }
      d *= 0.125f;
      p[j] = d;
      lmax = fmaxf(lmax, d);
    }
    red[t] = lmax; __syncthreads();
    for(int o=128;o>0;o>>=1){ if(t<o) red[t] = fmaxf(red[t], red[t+o]); __syncthreads(); }
    float m = red[0];
    __syncthreads();
    float lsum = 0.f;
    for(int j=t;j<nk;j+=256){ float e = expf(p[j]-m); p[j] = e; lsum += e; }
    red[t] = lsum; __syncthreads();
    for(int o=128;o>0;o>>=1){ if(t<o) red[t] += red[t+o]; __syncthreads(); }
    float inv = 1.0f/red[0];
    __syncthreads();
    int d = t & 63, g = t >> 6;
    float acc = 0.f;
    for(int j=g;j<nk;j+=4) acc += p[j]*bf2f(qkv[(size_t)j*3072 + 2048 + h*64 + d]);
    red[t] = acc; __syncthreads();
    if(g == 0){
      float o4 = red[d] + red[64+d] + red[128+d] + red[192+d];
      outp[(size_t)q*HD + h*64 + d] = f2bf(o4*inv);
    }
    __syncthreads();
  }
}

// ----------------- value head finish (4 slices, fused final outputs) -----------------
__global__ __launch_bounds__(256) void k_vpfin(const u16* __restrict__ P, const float* __restrict__ vb1,
                                               const float* __restrict__ vw2, const float* __restrict__ vb2,
                                               const float* __restrict__ rew, float* __restrict__ outp){
  __shared__ float red[256];
  int r = blockIdx.x, t = threadIdx.x;
  float s = 0.f;
  for(int c4=t;c4<1024;c4+=256){
    float4 v = unpk4(*(const u64*)&P[(size_t)r*4096 + c4*4]);
    #pragma unroll
    for(int z=1;z<4;++z){
      float4 q = unpk4(*(const u64*)&P[((size_t)z*129 + r)*4096 + c4*4]);
      v.x += q.x; v.y += q.y; v.z += q.z; v.w += q.w;
    }
    float4 b4 = *(const float4*)&vb1[c4*4];
    float4 w4 = *(const float4*)&vw2[c4*4];
    s += gelu_f(v.x + b4.x)*w4.x + gelu_f(v.y + b4.y)*w4.y
       + gelu_f(v.z + b4.z)*w4.z + gelu_f(v.w + b4.w)*w4.w;
  }
  red[t]=s; __syncthreads();
  for(int o=128;o>0;o>>=1){ if(t<o) red[t]+=red[t+o]; __syncthreads(); }
  if(t == 0){
    float val = red[0] + vb2[0];
    if(r == KS) outp[OUT_VP] = val;
    else { float d = val - rew[r]; outp[OUT_LOSS + r] = d*d; }
  }
}

extern "C" void kernel_launch(void* const* d_in, const int* in_sizes, int n_in,
                              void* d_out, int out_size, void* d_ws, size_t ws_size,
                              hipStream_t stream){
  const float* x     = (const float*)d_in[0];
  const float* mv    = (const float*)d_in[1];
  const float* mnv   = (const float*)d_in[2];
  const float* surp  = (const float*)d_in[3];
  const float* mrew  = (const float*)d_in[4];
  const float* noise = (const float*)d_in[5];
  const int*   aim   = (const int*)d_in[6];
  const int*   ait   = (const int*)d_in[7];
  const float* start = (const float*)d_in[8];
  const float* pos   = (const float*)d_in[9];
  const float* inW = (const float*)d_in[10]; const float* inB = (const float*)d_in[11];
  const float* oW  = (const float*)d_in[12]; const float* oB  = (const float*)d_in[13];
  const float* l1w = (const float*)d_in[14]; const float* l1b = (const float*)d_in[15];
  const float* l2w = (const float*)d_in[16]; const float* l2b = (const float*)d_in[17];
  const float* f1w = (const float*)d_in[18]; const float* f1b = (const float*)d_in[19];
  const float* f2w = (const float*)d_in[20]; const float* f2b = (const float*)d_in[21];
  const float* amw1= (const float*)d_in[22]; const float* amb1= (const float*)d_in[23];
  const float* amw2= (const float*)d_in[24]; const float* amb2= (const float*)d_in[25];
  const float* atw1= (const float*)d_in[26]; const float* atb1= (const float*)d_in[27];
  const float* atw2= (const float*)d_in[28]; const float* atb2= (const float*)d_in[29];
  const float* vw1 = (const float*)d_in[30]; const float* vb1 = (const float*)d_in[31];
  const float* vw2 = (const float*)d_in[32]; const float* vb2 = (const float*)d_in[33];

  float* out = (float*)d_out;
  char* ws = (char*)d_ws;
  u32*  hist3 = (u32*)(ws+OFF_H3);
  u32*  cnt3  = (u32*)(ws+OFF_C3);
  u32*  histS = (u32*)(ws+OFF_HS);
  u32*  tctr  = (u32*)(ws+OFF_CTR);
  u32*  bsum  = (u32*)(ws+OFF_BS);
  u32*  pref3 = (u32*)(ws+OFF_P3);
  u32*  keys3 = (u32*)(ws+OFF_K3);
  u16*  lo3   = (u16*)(ws+OFF_L3);
  u32*  keysS = (u32*)(ws+OFF_KSC);
  int*  idxb  = (int*)(ws+OFF_IDX);
  float* rew  = (float*)(ws+OFF_REW);
  u16*  hm    = (u16*)(ws+OFF_HM);
  u16*  ht    = (u16*)(ws+OFF_HT);
  float* vecs = (float*)(ws+OFF_VECS);
  u16*  lnb   = (u16*)(ws+OFF_LNB);
  u16*  qkvb  = (u16*)(ws+OFF_QKV);
  u16*  attn  = (u16*)(ws+OFF_ATT);
  u16*  ffh   = (u16*)(ws+OFF_FFH);
  u16*  vhin  = (u16*)(ws+OFF_VHIN);
  u16*  wb    = (u16*)(ws+OFF_WB);
  u16*  part  = (u16*)(ws+OFF_PART);
  u16*  part2 = part + (size_t)8*KS*HD;

  u16* inW_bf = wb + WB_IN;
  u16* oW_bf  = wb + WB_O;
  u16* f1w_bf = wb + WB_F1;
  u16* f2w_bf = wb + WB_F2;
  u16* am_bf  = wb + WB_AM;
  u16* at_bf  = wb + WB_AT;
  u16* vh_bf  = wb + WB_VH;

  dim3 b256(256);
  int gN = NM/256;

  // ---- weight conversion + hist/counter zeroing (one kernel) ----
  {
    WCA a;
    const float* srcs[7] = { inW, oW, f1w, f2w, amw2, atw2, vw1 };
    u16* dsts[7] = { inW_bf, oW_bf, f1w_bf, f2w_bf, am_bf, at_bf, vh_bf };
    u32 sizes4[7] = { 4*3*HD*HD/4, 4*HD*HD/4, 4*4*HD*HD/4, 4*4*HD*HD/4, HD*HD/4, HD*HD/4, 4*HD*HD/4 };
    u32 cum = 0;
    for(int j=0;j<7;++j){
      a.seg[j].s = srcs[j]; a.seg[j].d = dsts[j];
      a.seg[j].base4 = cum; cum += sizes4[j]; a.seg[j].end4 = cum;
    }
    a.tot4 = cum;
    a.z = (u32*)ws;
    hipLaunchKernelGGL(k_wconv, dim3((cum + 255)/256), b256, 0, stream, a);
  }

  // ---- scoring / ranking / top-k ----
  hipLaunchKernelGGL(k_simkey, dim3(NM/8), b256, 0, stream, mv, x, surp, noise, keys3, hist3);
  hipLaunchKernelGGL(k_scanA, dim3(192), b256, 0, stream, hist3, bsum);
  hipLaunchKernelGGL(k_scanC, dim3(192), b256, 0, stream, hist3, bsum, pref3);
  hipLaunchKernelGGL(k_scatter3, dim3(gN), b256, 0, stream, keys3, pref3, cnt3, lo3);
  hipLaunchKernelGGL(k_rank3score, dim3(gN), b256, 0, stream, keys3, pref3, lo3, keysS, histS);
  hipLaunchKernelGGL(k_selsort, dim3(1), dim3(1024), 0, stream, histS, keysS, idxb);

  // ---- gather + action MLPs + assembly/LN1 ----
  hipLaunchKernelGGL(k_gather, dim3(KS+1), b256, 0, stream, idxb, mv, mnv, mrew, aim, ait,
                     amw1, amb1, atw1, atb1, start, x, pos,
                     vecs, out + OUT_NEXT, hm, ht, rew, out + OUT_REWO);
  hipLaunchKernelGGL(k_actgemm, dim3(512), b256, 0, stream, hm, ht, am_bf, at_bf, part, part2);
  hipLaunchKernelGGL(k_finavln, dim3(SQ), b256, 0, stream, part, part2, amb2, atb2, pos, vecs, l1w, l1b, lnb);

  // ---- transformer (qkv/ffn1 self-finalizing S=4; o-proj/ffn2 S=8 + finrow) ----
  for(int l=0;l<NL;++l){
    hipLaunchKernelGGL((k_gemmF<4,0>), dim3(960), b256, 0, stream, lnb, inW_bf + (size_t)l*3*HD*HD,
                       part, inB + (size_t)l*3*HD, qkvb, tctr + (size_t)l*1024, SQ, 3*HD, HD, 5, HD);
    hipLaunchKernelGGL(k_attn, dim3(SQ/2, 16), b256, 0, stream, qkvb, attn);
    hipLaunchKernelGGL(k_gemm, dim3(640), b256, 0, stream, attn, oW_bf + (size_t)l*HD*HD, part, SQ, HD, HD, 8, 5, HD);
    hipLaunchKernelGGL((k_finrow<8,true>), dim3(SQ), b256, 0, stream, part, oB + (size_t)l*HD, vecs,
                       l2w + (size_t)l*HD, l2b + (size_t)l*HD, lnb, (float*)nullptr, (u16*)nullptr);
    hipLaunchKernelGGL((k_gemmF<4,1>), dim3(1280), b256, 0, stream, lnb, f1w_bf + (size_t)l*4*HD*HD,
                       part, f1b + (size_t)l*4*HD, ffh, tctr + (size_t)l*1024 + 512, SQ, 4*HD, HD, 5, HD);
    hipLaunchKernelGGL(k_gemm, dim3(640), b256, 0, stream, ffh, f2w_bf + (size_t)l*HD*4*HD, part, SQ, HD, 4*HD, 8, 5, 4*HD);
    if(l < NL-1)
      hipLaunchKernelGGL((k_finrow<8,true>), dim3(SQ), b256, 0, stream, part, f2b + (size_t)l*HD, vecs,
                         l1w + (size_t)(l+1)*HD, l1b + (size_t)(l+1)*HD, lnb, (float*)nullptr, (u16*)nullptr);
    else
      hipLaunchKernelGGL((k_finrow<8,false>), dim3(SQ), b256, 0, stream, part, f2b + (size_t)l*HD, vecs,
                         (const float*)nullptr, (const float*)nullptr, (u16*)nullptr, out, vhin);
  }

  // ---- value head: S=4, 768 blocks ----
  hipLaunchKernelGGL(k_gemm, dim3(768), b256, 0, stream, vhin, vh_bf, part, KS+1, 4*HD, HD, 4, 3, HD);
  hipLaunchKernelGGL(k_vpfin, dim3(KS+1), b256, 0, stream, part, vb1, vw2, vb2, rew, out);
}

// Round 16
// 825.537 us; speedup vs baseline: 2.6373x; 2.6373x over previous
//
#include <hip/hip_runtime.h>
#include <hip/hip_bf16.h>
#include <math.h>
#include <stdint.h>

typedef unsigned int u32;
typedef unsigned short u16;
typedef unsigned long long u64;

#define NM   65536
#define HD   1024
#define KS   128
#define SQ   258
#define NL   4
#define NBIN 65536
#define CCAP 2048

using bf16x8 = __attribute__((ext_vector_type(8))) short;
using f32x4v = __attribute__((ext_vector_type(4))) float;

static constexpr size_t A256(size_t x){ return (x + 255) & ~(size_t)255; }

// ---- zeroed region (folded into k_wconv): hist3 + cnt3 + histS = 1792 KB ----
constexpr size_t OFF_H3   = 0;
constexpr size_t OFF_C3   = OFF_H3 + (size_t)3*NBIN*4;
constexpr size_t OFF_HS   = OFF_C3 + (size_t)3*NBIN*4;
constexpr size_t ZERO_BYTES = OFF_HS + (size_t)NBIN*4;
constexpr u32 ZBLK = 1792;
// ---- rest ----
constexpr size_t OFF_BS   = A256(ZERO_BYTES);
constexpr size_t OFF_P3   = A256(OFF_BS + 192*4);
constexpr size_t OFF_K3   = A256(OFF_P3 + (size_t)3*(NBIN+1)*4);
constexpr size_t OFF_L3   = A256(OFF_K3 + (size_t)3*NM*4);            // u16 lo3
constexpr size_t OFF_KSC  = A256(OFF_L3 + (size_t)3*NM*2);
constexpr size_t OFF_IDX  = A256(OFF_KSC + (size_t)NM*4);
constexpr size_t OFF_REW  = A256(OFF_IDX  + (size_t)KS*4);
constexpr size_t OFF_HM   = A256(OFF_REW  + (size_t)KS*4);
constexpr size_t OFF_HT   = A256(OFF_HM   + (size_t)KS*HD*2);
constexpr size_t OFF_VECS = A256(OFF_HT   + (size_t)KS*HD*2);
constexpr size_t OFF_LNB  = A256(OFF_VECS + (size_t)SQ*HD*4);
constexpr size_t OFF_QKV  = A256(OFF_LNB  + (size_t)SQ*HD*2);
constexpr size_t OFF_ATT  = A256(OFF_QKV  + (size_t)SQ*3*HD*2);
constexpr size_t OFF_FFH  = A256(OFF_ATT  + (size_t)SQ*HD*2);
constexpr size_t OFF_VHIN = A256(OFF_FFH  + (size_t)SQ*4*HD*2);
constexpr size_t OFF_WB   = A256(OFF_VHIN + (size_t)129*HD*2);
constexpr size_t NWELEM   = 56623104;
constexpr size_t OFF_PART = A256(OFF_WB + NWELEM*2);

constexpr size_t WB_IN = 0;
constexpr size_t WB_O  = WB_IN + (size_t)4*3*HD*HD;
constexpr size_t WB_F1 = WB_O  + (size_t)4*HD*HD;
constexpr size_t WB_F2 = WB_F1 + (size_t)4*4*HD*HD;
constexpr size_t WB_AM = WB_F2 + (size_t)4*4*HD*HD;
constexpr size_t WB_AT = WB_AM + (size_t)HD*HD;
constexpr size_t WB_VH = WB_AT + (size_t)HD*HD;

// output layout (floats)
constexpr int OUT_NEXT = 257*HD;
constexpr int OUT_VP   = OUT_NEXT + KS*HD;
constexpr int OUT_LOSS = OUT_VP + 1;
constexpr int OUT_REWO = OUT_LOSS + KS;

__device__ __forceinline__ float gelu_f(float v){
  return 0.5f*v*(1.0f + erff(v*0.70710678118654752440f));
}

__device__ __forceinline__ u16 f2bf(float f){
  __hip_bfloat16 h = __float2bfloat16(f);
  u16 s; __builtin_memcpy(&s, &h, sizeof(u16));
  return s;
}

__device__ __forceinline__ float bf2f(u16 v){ return __uint_as_float(((u32)v) << 16); }

__device__ __forceinline__ float4 unpk4(u64 pk){
  u32 lo = (u32)pk, hi = (u32)(pk >> 32);
  float4 v;
  v.x = __uint_as_float(lo << 16);
  v.y = __uint_as_float(lo & 0xFFFF0000u);
  v.z = __uint_as_float(hi << 16);
  v.w = __uint_as_float(hi & 0xFFFF0000u);
  return v;
}

__device__ __forceinline__ u64 pk4(float4 v){
  u16 r[4] = { f2bf(v.x), f2bf(v.y), f2bf(v.z), f2bf(v.w) };
  u64 pk; __builtin_memcpy(&pk, r, 8);
  return pk;
}

__device__ __forceinline__ u32 fkey(float v){
  u32 b = __float_as_uint(v);
  return (b >> 31) ? ~b : (b | 0x80000000u);
}

__device__ __forceinline__ void gload16(const u16* g, u16* l){
  __builtin_amdgcn_global_load_lds(
      (const __attribute__((address_space(1))) unsigned int*)g,
      (__attribute__((address_space(3))) unsigned int*)l, 16, 0, 0);
}

// ----------------- weight conversion fp32 -> bf16 (+ zero hist regions) -----------------
struct WSeg { const float* s; u16* d; u32 base4, end4; };
struct WCA { WSeg seg[7]; u32 tot4; u32* z; };
__global__ __launch_bounds__(256) void k_wconv(WCA a){
  if(blockIdx.x < ZBLK) a.z[blockIdx.x*256 + threadIdx.x] = 0u;
  u32 i = blockIdx.x*256 + threadIdx.x;
  if(i >= a.tot4) return;
  #pragma unroll
  for(int j=0;j<7;++j){
    if(i < a.seg[j].end4){
      u32 off = i - a.seg[j].base4;
      float4 v = *(const float4*)&a.seg[j].s[(size_t)off*4];
      *(u64*)&a.seg[j].d[(size_t)off*4] = pk4(v);
      return;
    }
  }
}

// ----------------- fused xnorm + sim + keys + hist (8 rows/block) -----------------
__global__ __launch_bounds__(256) void k_simkey(const float* __restrict__ mv, const float* __restrict__ x,
                                                const float* __restrict__ surp, const float* __restrict__ noise,
                                                u32* __restrict__ keys3, u32* __restrict__ hist3){
  __shared__ float xs[HD];
  __shared__ float red[256];
  int t = threadIdx.x;
  float s = 0.f;
  for(int i=t;i<HD;i+=256){ float v=x[i]; s += v*v; }
  red[t]=s; __syncthreads();
  for(int o=128;o>0;o>>=1){ if(t<o) red[t]+=red[t+o]; __syncthreads(); }
  float nrm = fmaxf(sqrtf(red[0]), 1e-8f);
  for(int i=t;i<HD;i+=256) xs[i] = x[i]/nrm;
  __syncthreads();
  int lane = t & 63, w = t >> 6;
  #pragma unroll
  for(int rep=0;rep<2;++rep){
    int row = blockIdx.x*8 + rep*4 + w;
    const float4* p = (const float4*)(mv + (size_t)row*HD);
    const float4* q = (const float4*)xs;
    float d=0.f, ss=0.f;
    #pragma unroll
    for(int r=0;r<4;++r){
      float4 v = p[lane + 64*r]; float4 u = q[lane + 64*r];
      d  += v.x*u.x + v.y*u.y + v.z*u.z + v.w*u.w;
      ss += v.x*v.x + v.y*v.y + v.z*v.z + v.w*v.w;
    }
    for(int off=32;off>0;off>>=1){ d += __shfl_xor(d,off,64); ss += __shfl_xor(ss,off,64); }
    if(lane==0){
      float sim = d / fmaxf(sqrtf(ss),1e-8f);
      float vals[3] = { surp[row], sim, noise[row] };
      #pragma unroll
      for(int a=0;a<3;++a){
        u32 k = fkey(vals[a]);
        keys3[(size_t)a*NM + row] = k;
        atomicAdd(&hist3[(size_t)a*NBIN + (k >> 16)], 1u);
      }
    }
  }
}

// ----------------- scan: A (block sums) + C (inline base, per-chunk prefix) -----------------
__global__ __launch_bounds__(256) void k_scanA(const u32* __restrict__ hist3, u32* __restrict__ bsum){
  __shared__ u32 red[256];
  int blk = blockIdx.x;
  int t = threadIdx.x;
  const u32* h = hist3 + (size_t)(blk>>6)*NBIN + (size_t)(blk&63)*1024;
  u32 s = 0;
  #pragma unroll
  for(int j=0;j<4;++j) s += h[t*4+j];
  red[t]=s; __syncthreads();
  for(int o=128;o>0;o>>=1){ if(t<o) red[t]+=red[t+o]; __syncthreads(); }
  if(t==0) bsum[blk] = red[0];
}

__global__ __launch_bounds__(256) void k_scanC(const u32* __restrict__ hist3, const u32* __restrict__ bsum,
                                               u32* __restrict__ pref3){
  __shared__ u32 part[256];
  int blk = blockIdx.x;
  int t = threadIdx.x;
  int a = blk >> 6, c = blk & 63;
  u32 base = 0;
  for(int j=0;j<c;++j) base += bsum[a*64 + j];
  const u32* h = hist3 + (size_t)a*NBIN + (size_t)c*1024;
  u32* pref = pref3 + (size_t)a*(NBIN+1) + (size_t)c*1024;
  u32 loc[4]; u32 s = 0;
  #pragma unroll
  for(int j=0;j<4;++j){ loc[j] = h[t*4+j]; s += loc[j]; }
  part[t] = s; __syncthreads();
  for(int off=1;off<256;off<<=1){
    u32 u = (t >= off) ? part[t-off] : 0u;
    __syncthreads(); part[t] += u; __syncthreads();
  }
  u32 run = base + part[t] - s;
  #pragma unroll
  for(int j=0;j<4;++j){ pref[t*4+j] = run; run += loc[j]; }
  if(c == 63 && t == 255) pref3[(size_t)a*(NBIN+1) + NBIN] = NM;
}

// ----------------- scatter / rank+score -----------------
__global__ void k_scatter3(const u32* __restrict__ keys3, const u32* __restrict__ pref3,
                           u32* __restrict__ cnt3, u16* __restrict__ lo3){
  int i = blockIdx.x*256 + threadIdx.x;
  if(i >= NM) return;
  #pragma unroll
  for(int a=0;a<3;++a){
    u32 k = keys3[(size_t)a*NM + i];
    u32 b = k >> 16;
    u32 pos = pref3[(size_t)a*(NBIN+1) + b] + atomicAdd(&cnt3[(size_t)a*NBIN + b], 1u);
    lo3[(size_t)a*NM + pos] = (u16)(k & 0xFFFFu);
  }
}

__global__ void k_rank3score(const u32* __restrict__ keys3, const u32* __restrict__ pref3,
                             const u16* __restrict__ lo3, u32* __restrict__ keysS, u32* __restrict__ histS){
  int i = blockIdx.x*256 + threadIdx.x;
  if(i >= NM) return;
  float rr[3];
  #pragma unroll
  for(int a=0;a<3;++a){
    u32 k = keys3[(size_t)a*NM + i];
    u32 b = k >> 16, my = k & 0xFFFFu;
    const u32* pref = pref3 + (size_t)a*(NBIN+1);
    const u16* lo = lo3 + (size_t)a*NM;
    u32 s = pref[b], e = pref[b+1];
    u32 nl = 0, ne = 0;
    for(u32 j=s;j<e;++j){ u32 u = lo[j]; nl += (u < my); ne += (u == my); }
    u32 left = s + nl, right = left + ne;
    rr[a] = (float)(left + right - 1) * (1.0f/131072.0f);
  }
  float sc = __fadd_rn(__fadd_rn(__fmul_rn(rr[0],rr[0]), __fmul_rn(rr[1],rr[1])), __fmul_rn(rr[2],rr[2]));
  u32 k = __float_as_uint(sc);
  keysS[i] = k;
  atomicAdd(&histS[k >> 16], 1u);
}

// ----------------- fused threshold + collect + bitonic sort -----------------
__global__ __launch_bounds__(1024) void k_selsort(const u32* __restrict__ histS, const u32* __restrict__ keysS,
                                                  int* __restrict__ idx){
  __shared__ u32 part[1024];
  __shared__ u64 sm[CCAP];
  __shared__ u32 thrT, cnt;
  int t = threadIdx.x;
  u32 base = t*64, s = 0;
  for(int j=0;j<64;++j) s += histS[base+j];
  part[t] = s; __syncthreads();
  for(int off=1;off<1024;off<<=1){
    u32 v = (t+off < 1024) ? part[t+off] : 0u;
    __syncthreads(); part[t] += v; __syncthreads();
  }
  u32 above = part[t] - s;
  if(above < (u32)KS && above + s >= (u32)KS){
    u32 cum = above;
    for(int j=63;j>=0;--j){
      u32 c = histS[base+j];
      if(cum + c >= (u32)KS){ thrT = (u32)(base+j) << 16; cnt = 0; break; }
      cum += c;
    }
  }
  __syncthreads();
  u32 T = thrT;
  for(int i=t;i<NM;i+=1024){
    u32 k = keysS[i];
    if(k >= T){
      u32 p = atomicAdd(&cnt, 1u);
      if(p < (u32)CCAP) sm[p] = ((u64)(~k) << 32) | (u32)i;
    }
  }
  __syncthreads();
  u32 n = cnt; if(n > (u32)CCAP) n = CCAP;
  for(int i=t;i<CCAP;i+=1024) if(i >= (int)n) sm[i] = 0xFFFFFFFFFFFFFFFFull;
  __syncthreads();
  for(int k=2;k<=CCAP;k<<=1){
    for(int j=k>>1;j>0;j>>=1){
      for(int i=t;i<CCAP;i+=1024){
        int ixj = i ^ j;
        if(ixj > i){
          bool up = ((i & k) == 0);
          u64 a = sm[i], b = sm[ixj];
          if((a > b) == up){ sm[i] = b; sm[ixj] = a; }
        }
      }
      __syncthreads();
    }
  }
  if(t < KS) idx[t] = (int)(sm[t] & 0xFFFFFFFFu);
}

// ----------------- gather -----------------
__global__ void k_gather(const int* __restrict__ idx,
                         const float* __restrict__ mv, const float* __restrict__ mnv,
                         const float* __restrict__ mrew,
                         const int* __restrict__ aim, const int* __restrict__ ait,
                         const float* __restrict__ amw1, const float* __restrict__ amb1,
                         const float* __restrict__ atw1, const float* __restrict__ atb1,
                         const float* __restrict__ start, const float* __restrict__ x,
                         const float* __restrict__ pos,
                         float* __restrict__ vecs, float* __restrict__ outnext,
                         u16* __restrict__ hm, u16* __restrict__ ht,
                         float* __restrict__ rew, float* __restrict__ outrew){
  int k = blockIdx.x;
  int t = threadIdx.x;
  if(k < KS){
    int row = idx[k];
    const float4* a = (const float4*)(mv  + (size_t)row*HD);
    const float4* b = (const float4*)(mnv + (size_t)row*HD);
    const float4* pz = (const float4*)(pos + (size_t)(2*k+1)*HD);
    float4* vr = (float4*)(vecs + (size_t)(2*k+1)*HD);
    float4* on = (float4*)(outnext + (size_t)k*HD);
    float4 av = a[t], bv = b[t], pv = pz[t];
    av.x += pv.x; av.y += pv.y; av.z += pv.z; av.w += pv.w;
    vr[t] = av; on[t] = bv;
    int am = aim[row], at = ait[row];
    for(int j=t;j<HD;j+=256){
      hm[(size_t)k*HD+j] = f2bf(gelu_f(amw1[(size_t)j*9 + am] + amb1[j]));
      ht[(size_t)k*HD+j] = f2bf(gelu_f(atw1[(size_t)j*4 + at] + atb1[j]));
    }
    if(t == 0){ float r = mrew[row]; rew[k] = r; outrew[k] = r; }
  } else {
    const float4* st = (const float4*)start;
    const float4* xx = (const float4*)x;
    const float4* p0 = (const float4*)pos;
    const float4* p1 = (const float4*)(pos + (size_t)(SQ-1)*HD);
    float4 v0 = st[t], v1 = xx[t], q0 = p0[t], q1 = p1[t];
    v0.x += q0.x; v0.y += q0.y; v0.z += q0.z; v0.w += q0.w;
    v1.x += q1.x; v1.y += q1.y; v1.z += q1.z; v1.w += q1.w;
    ((float4*)vecs)[t] = v0;
    ((float4*)(vecs + (size_t)(SQ-1)*HD))[t] = v1;
  }
}

// ----------------- bf16 MFMA split-K GEMM, BK=64 (global_load_lds, dbuf) -> bf16 partials -----------------
__device__ __forceinline__ void gemm_body(u16* As, u16* Bs, const u16* __restrict__ A, const u16* __restrict__ B,
        u16* __restrict__ P, int M, int N, int K, int S, int nbm, int lda, int tile){
  int bm = (tile % nbm) * 64;
  int tmp = tile / nbm;
  int z  = tmp % S;
  int bn = (tmp / S) * 64;
  int Ks = K / S, kbeg = z*Ks;
  int nk = Ks >> 6;

  int t = threadIdx.x, lane = t & 63, w = t >> 6;
  int s0 = w*64 + lane, s1 = s0 + 256;
  int r0s = s0 >> 3, c0s = (s0 & 7) ^ (r0s & 7);
  int r1s = s1 >> 3, c1s = (s1 & 7) ^ (r1s & 7);
  const u16* ga0 = A + (size_t)(bm + r0s)*lda + kbeg + c0s*8;
  const u16* ga1 = A + (size_t)(bm + r1s)*lda + kbeg + c1s*8;
  const u16* gb0 = B + (size_t)(bn + r0s)*K  + kbeg + c0s*8;
  const u16* gb1 = B + (size_t)(bn + r1s)*K  + kbeg + c1s*8;
  int lb0 = w*512, lb1 = 2048 + w*512;

  int wm = (w >> 1)*32, wn = (w & 1)*32;
  int lr = lane & 15, lg = lane >> 4;
  int ra0 = wm + lr, ra1 = ra0 + 16;
  int rb0 = wn + lr, rb1 = rb0 + 16;
  int a00 = ra0*64 + ((lg     ^ (ra0&7))*8);
  int a01 = ra0*64 + (((4+lg) ^ (ra0&7))*8);
  int a10 = ra1*64 + ((lg     ^ (ra1&7))*8);
  int a11 = ra1*64 + (((4+lg) ^ (ra1&7))*8);
  int b00 = rb0*64 + ((lg     ^ (rb0&7))*8);
  int b01 = rb0*64 + (((4+lg) ^ (rb0&7))*8);
  int b10 = rb1*64 + ((lg     ^ (rb1&7))*8);
  int b11 = rb1*64 + (((4+lg) ^ (rb1&7))*8);

  f32x4v acc00 = {0,0,0,0}, acc01 = {0,0,0,0}, acc10 = {0,0,0,0}, acc11 = {0,0,0,0};

  gload16(ga0, As + lb0); gload16(ga1, As + lb1);
  gload16(gb0, Bs + lb0); gload16(gb1, Bs + lb1);
  ga0 += 64; ga1 += 64; gb0 += 64; gb1 += 64;
  __syncthreads();

  for(int kk = 0; kk < nk; ++kk){
    int cur = (kk & 1) << 12;
    if(kk + 1 < nk){
      int nxt = cur ^ 4096;
      gload16(ga0, As + nxt + lb0); gload16(ga1, As + nxt + lb1);
      gload16(gb0, Bs + nxt + lb0); gload16(gb1, Bs + nxt + lb1);
      ga0 += 64; ga1 += 64; gb0 += 64; gb1 += 64;
    }
    bf16x8 xa0 = *(const bf16x8*)&As[cur + a00];
    bf16x8 xa1 = *(const bf16x8*)&As[cur + a10];
    bf16x8 xb0 = *(const bf16x8*)&Bs[cur + b00];
    bf16x8 xb1 = *(const bf16x8*)&Bs[cur + b10];
    acc00 = __builtin_amdgcn_mfma_f32_16x16x32_bf16(xa0, xb0, acc00, 0, 0, 0);
    acc01 = __builtin_amdgcn_mfma_f32_16x16x32_bf16(xa0, xb1, acc01, 0, 0, 0);
    acc10 = __builtin_amdgcn_mfma_f32_16x16x32_bf16(xa1, xb0, acc10, 0, 0, 0);
    acc11 = __builtin_amdgcn_mfma_f32_16x16x32_bf16(xa1, xb1, acc11, 0, 0, 0);
    xa0 = *(const bf16x8*)&As[cur + a01];
    xa1 = *(const bf16x8*)&As[cur + a11];
    xb0 = *(const bf16x8*)&Bs[cur + b01];
    xb1 = *(const bf16x8*)&Bs[cur + b11];
    acc00 = __builtin_amdgcn_mfma_f32_16x16x32_bf16(xa0, xb0, acc00, 0, 0, 0);
    acc01 = __builtin_amdgcn_mfma_f32_16x16x32_bf16(xa0, xb1, acc01, 0, 0, 0);
    acc10 = __builtin_amdgcn_mfma_f32_16x16x32_bf16(xa1, xb0, acc10, 0, 0, 0);
    acc11 = __builtin_amdgcn_mfma_f32_16x16x32_bf16(xa1, xb1, acc11, 0, 0, 0);
    __syncthreads();
  }

  size_t zbase = (size_t)z * (size_t)M;
  #pragma unroll
  for(int r=0;r<4;++r){
    int row0 = bm + wm + lg*4 + r;
    int row1 = row0 + 16;
    int cc0 = bn + wn + lr, cc1 = cc0 + 16;
    if(row0 < M){
      P[(zbase+row0)*N + cc0] = f2bf(acc00[r]);
      P[(zbase+row0)*N + cc1] = f2bf(acc01[r]);
    }
    if(row1 < M){
      P[(zbase+row1)*N + cc0] = f2bf(acc10[r]);
      P[(zbase+row1)*N + cc1] = f2bf(acc11[r]);
    }
  }
}

__global__ __launch_bounds__(256) void k_gemm(const u16* __restrict__ A, const u16* __restrict__ B,
        u16* __restrict__ P, int M, int N, int K, int S, int nbm, int lda){
  __shared__ u16 As[8192];
  __shared__ u16 Bs[8192];
  u32 nwg = gridDim.x, orig = blockIdx.x;
  u32 swz = (orig & 7)*(nwg >> 3) + (orig >> 3);
  gemm_body(As, Bs, A, B, P, M, N, K, S, nbm, lda, (int)swz);
}

__global__ __launch_bounds__(256) void k_actgemm(const u16* __restrict__ hm, const u16* __restrict__ ht,
        const u16* __restrict__ amw2, const u16* __restrict__ atw2,
        u16* __restrict__ part, u16* __restrict__ part2){
  __shared__ u16 As[8192];
  __shared__ u16 Bs[8192];
  int which = blockIdx.x >> 8, tile = blockIdx.x & 255;
  gemm_body(As, Bs, which ? ht : hm, which ? atw2 : amw2, which ? part2 : part,
            KS, HD, HD, 8, 2, HD, tile);
}

// ----------------- flat epilogue: sum S_ bf16 slices + bias (+gelu) -----------------
template<int S_, int ACT, bool BFOUT>
__global__ __launch_bounds__(256) void k_finS(const u16* __restrict__ P, const float* __restrict__ bias,
                                              float* __restrict__ C, u16* __restrict__ Cb, int MN4, int Nd){
  int i4 = blockIdx.x*256 + threadIdx.x;
  if(i4 >= MN4) return;
  size_t off = (size_t)i4*4;
  size_t MN = (size_t)MN4*4;
  float4 v = unpk4(*(const u64*)&P[off]);
  #pragma unroll
  for(int z=1;z<S_;++z){
    float4 q = unpk4(*(const u64*)&P[(size_t)z*MN + off]);
    v.x += q.x; v.y += q.y; v.z += q.z; v.w += q.w;
  }
  int j = (i4 % (Nd/4))*4;
  float4 b4 = *(const float4*)&bias[j];
  v.x += b4.x; v.y += b4.y; v.z += b4.z; v.w += b4.w;
  if(ACT == 1){ v.x = gelu_f(v.x); v.y = gelu_f(v.y); v.z = gelu_f(v.z); v.w = gelu_f(v.w); }
  if(BFOUT) *(u64*)&Cb[off] = pk4(v);
  else      *(float4*)&C[off] = v;
}

// ----------------- row finish: sum S_ bf16 slices + bias + residual; LN | copy-out -----------------
template<int S_, bool LN>
__global__ __launch_bounds__(256) void k_finrow(const u16* __restrict__ P, const float* __restrict__ bias,
                                                float* __restrict__ vecs, const float* __restrict__ lw,
                                                const float* __restrict__ lb, u16* __restrict__ lnb,
                                                float* __restrict__ outp, u16* __restrict__ vhin){
  __shared__ float red[256];
  int row = blockIdx.x, t = threadIdx.x;
  int j = t*4;
  float4 v = unpk4(*(const u64*)&P[(size_t)row*HD + j]);
  #pragma unroll
  for(int z=1;z<S_;++z){
    float4 p = unpk4(*(const u64*)&P[((size_t)z*SQ + row)*HD + j]);
    v.x += p.x; v.y += p.y; v.z += p.z; v.w += p.w;
  }
  float4 b4 = *(const float4*)&bias[j];
  float4 r4 = *(const float4*)&vecs[(size_t)row*HD + j];
  v.x += b4.x + r4.x; v.y += b4.y + r4.y; v.z += b4.z + r4.z; v.w += b4.w + r4.w;
  *(float4*)&vecs[(size_t)row*HD + j] = v;
  if(LN){
    red[t] = v.x+v.y+v.z+v.w; __syncthreads();
    for(int o=128;o>0;o>>=1){ if(t<o) red[t]+=red[t+o]; __syncthreads(); }
    float m = red[0]*(1.0f/HD); __syncthreads();
    float dx=v.x-m, dy=v.y-m, dz=v.z-m, dw=v.w-m;
    red[t] = dx*dx+dy*dy+dz*dz+dw*dw; __syncthreads();
    for(int o=128;o>0;o>>=1){ if(t<o) red[t]+=red[t+o]; __syncthreads(); }
    float den = sqrtf(red[0]*(1.0f/HD) + 1e-5f);
    float4 w4 = *(const float4*)&lw[j];
    float4 lb4 = *(const float4*)&lb[j];
    float4 o4;
    o4.x = dx/den*w4.x + lb4.x; o4.y = dy/den*w4.y + lb4.y;
    o4.z = dz/den*w4.z + lb4.z; o4.w = dw/den*w4.w + lb4.w;
    *(u64*)&lnb[(size_t)row*HD + j] = pk4(o4);
  } else {
    if(row >= 1) *(float4*)&outp[(size_t)(row-1)*HD + j] = v;
    if(row & 1){
      int vr = (row-1) >> 1;
      *(u64*)&vhin[(size_t)vr*HD + j] = pk4(v);
    }
  }
}

// ----------------- finav + LN1 -----------------
__global__ __launch_bounds__(256) void k_finavln(const u16* __restrict__ Pm, const u16* __restrict__ Pt,
                                                 const float* __restrict__ bm_, const float* __restrict__ bt_,
                                                 const float* __restrict__ pos, float* __restrict__ vecs,
                                                 const float* __restrict__ lw, const float* __restrict__ lb,
                                                 u16* __restrict__ lnb){
  __shared__ float red[256];
  int row = blockIdx.x, t = threadIdx.x;
  int j = t*4;
  float4 v;
  if(row >= 2 && row <= 256 && ((row & 1) == 0)){
    int k = (row-2) >> 1;
    float4 s = {0,0,0,0};
    #pragma unroll
    for(int z=0;z<8;++z){
      float4 a = unpk4(*(const u64*)&Pm[((size_t)z*KS + k)*HD + j]);
      float4 b = unpk4(*(const u64*)&Pt[((size_t)z*KS + k)*HD + j]);
      s.x += a.x+b.x; s.y += a.y+b.y; s.z += a.z+b.z; s.w += a.w+b.w;
    }
    float4 bm4 = *(const float4*)&bm_[j];
    float4 bt4 = *(const float4*)&bt_[j];
    float4 p4 = *(const float4*)&pos[(size_t)row*HD + j];
    v.x = 0.5f*(s.x + bm4.x + bt4.x) + p4.x;
    v.y = 0.5f*(s.y + bm4.y + bt4.y) + p4.y;
    v.z = 0.5f*(s.z + bm4.z + bt4.z) + p4.z;
    v.w = 0.5f*(s.w + bm4.w + bt4.w) + p4.w;
    *(float4*)&vecs[(size_t)row*HD + j] = v;
  } else {
    v = *(const float4*)&vecs[(size_t)row*HD + j];
  }
  red[t] = v.x+v.y+v.z+v.w; __syncthreads();
  for(int o=128;o>0;o>>=1){ if(t<o) red[t]+=red[t+o]; __syncthreads(); }
  float m = red[0]*(1.0f/HD); __syncthreads();
  float dx=v.x-m, dy=v.y-m, dz=v.z-m, dw=v.w-m;
  red[t] = dx*dx+dy*dy+dz*dz+dw*dw; __syncthreads();
  for(int o=128;o>0;o>>=1){ if(t<o) red[t]+=red[t+o]; __syncthreads(); }
  float den = sqrtf(red[0]*(1.0f/HD) + 1e-5f);
  float4 w4 = *(const float4*)&lw[j];
  float4 lb4 = *(const float4*)&lb[j];
  float4 o4;
  o4.x = dx/den*w4.x + lb4.x; o4.y = dy/den*w4.y + lb4.y;
  o4.z = dz/den*w4.z + lb4.z; o4.w = dw/den*w4.w + lb4.w;
  *(u64*)&lnb[(size_t)row*HD + j] = pk4(o4);
}

// ----------------- attention (paired q for load balance; bf16 in/out) -----------------
__global__ void k_attn(const u16* __restrict__ qkv, u16* __restrict__ outp){
  __shared__ float qv[64];
  __shared__ float p[SQ];
  __shared__ float red[256];
  int h = blockIdx.y, t = threadIdx.x;
  #pragma unroll
  for(int half=0; half<2; ++half){
    int q = half ? (SQ-1 - (int)blockIdx.x) : (int)blockIdx.x;   // q and 257-q
    if(t < 64) qv[t] = bf2f(qkv[(size_t)q*3072 + h*64 + t]);
    __syncthreads();
    int nk = q + 1;
    float lmax = -1e30f;
    for(int j=t;j<nk;j+=256){
      const u32* kr = (const u32*)(qkv + (size_t)j*3072 + 1024 + h*64);
      float d = 0.f;
      #pragma unroll
      for(int c2=0;c2<32;++c2){
        u32 pk = kr[c2];
        d += qv[c2*2]   * __uint_as_float(pk << 16);
        d += qv[c2*2+1] * __uint_as_float(pk & 0xFFFF0000u);
      }
      d *= 0.125f;
      p[j] = d;
      lmax = fmaxf(lmax, d);
    }
    red[t] = lmax; __syncthreads();
    for(int o=128;o>0;o>>=1){ if(t<o) red[t] = fmaxf(red[t], red[t+o]); __syncthreads(); }
    float m = red[0];
    __syncthreads();
    float lsum = 0.f;
    for(int j=t;j<nk;j+=256){ float e = expf(p[j]-m); p[j] = e; lsum += e; }
    red[t] = lsum; __syncthreads();
    for(int o=128;o>0;o>>=1){ if(t<o) red[t] += red[t+o]; __syncthreads(); }
    float inv = 1.0f/red[0];
    __syncthreads();
    int d = t & 63, g = t >> 6;
    float acc = 0.f;
    for(int j=g;j<nk;j+=4) acc += p[j]*bf2f(qkv[(size_t)j*3072 + 2048 + h*64 + d]);
    red[t] = acc; __syncthreads();
    if(g == 0){
      float o4 = red[d] + red[64+d] + red[128+d] + red[192+d];
      outp[(size_t)q*HD + h*64 + d] = f2bf(o4*inv);
    }
    __syncthreads();
  }
}

// ----------------- value head finish (4 slices, fused final outputs) -----------------
__global__ __launch_bounds__(256) void k_vpfin(const u16* __restrict__ P, const float* __restrict__ vb1,
                                               const float* __restrict__ vw2, const float* __restrict__ vb2,
                                               const float* __restrict__ rew, float* __restrict__ outp){
  __shared__ float red[256];
  int r = blockIdx.x, t = threadIdx.x;
  float s = 0.f;
  for(int c4=t;c4<1024;c4+=256){
    float4 v = unpk4(*(const u64*)&P[(size_t)r*4096 + c4*4]);
    #pragma unroll
    for(int z=1;z<4;++z){
      float4 q = unpk4(*(const u64*)&P[((size_t)z*129 + r)*4096 + c4*4]);
      v.x += q.x; v.y += q.y; v.z += q.z; v.w += q.w;
    }
    float4 b4 = *(const float4*)&vb1[c4*4];
    float4 w4 = *(const float4*)&vw2[c4*4];
    s += gelu_f(v.x + b4.x)*w4.x + gelu_f(v.y + b4.y)*w4.y
       + gelu_f(v.z + b4.z)*w4.z + gelu_f(v.w + b4.w)*w4.w;
  }
  red[t]=s; __syncthreads();
  for(int o=128;o>0;o>>=1){ if(t<o) red[t]+=red[t+o]; __syncthreads(); }
  if(t == 0){
    float val = red[0] + vb2[0];
    if(r == KS) outp[OUT_VP] = val;
    else { float d = val - rew[r]; outp[OUT_LOSS + r] = d*d; }
  }
}

extern "C" void kernel_launch(void* const* d_in, const int* in_sizes, int n_in,
                              void* d_out, int out_size, void* d_ws, size_t ws_size,
                              hipStream_t stream){
  const float* x     = (const float*)d_in[0];
  const float* mv    = (const float*)d_in[1];
  const float* mnv   = (const float*)d_in[2];
  const float* surp  = (const float*)d_in[3];
  const float* mrew  = (const float*)d_in[4];
  const float* noise = (const float*)d_in[5];
  const int*   aim   = (const int*)d_in[6];
  const int*   ait   = (const int*)d_in[7];
  const float* start = (const float*)d_in[8];
  const float* pos   = (const float*)d_in[9];
  const float* inW = (const float*)d_in[10]; const float* inB = (const float*)d_in[11];
  const float* oW  = (const float*)d_in[12]; const float* oB  = (const float*)d_in[13];
  const float* l1w = (const float*)d_in[14]; const float* l1b = (const float*)d_in[15];
  const float* l2w = (const float*)d_in[16]; const float* l2b = (const float*)d_in[17];
  const float* f1w = (const float*)d_in[18]; const float* f1b = (const float*)d_in[19];
  const float* f2w = (const float*)d_in[20]; const float* f2b = (const float*)d_in[21];
  const float* amw1= (const float*)d_in[22]; const float* amb1= (const float*)d_in[23];
  const float* amw2= (const float*)d_in[24]; const float* amb2= (const float*)d_in[25];
  const float* atw1= (const float*)d_in[26]; const float* atb1= (const float*)d_in[27];
  const float* atw2= (const float*)d_in[28]; const float* atb2= (const float*)d_in[29];
  const float* vw1 = (const float*)d_in[30]; const float* vb1 = (const float*)d_in[31];
  const float* vw2 = (const float*)d_in[32]; const float* vb2 = (const float*)d_in[33];

  float* out = (float*)d_out;
  char* ws = (char*)d_ws;
  u32*  hist3 = (u32*)(ws+OFF_H3);
  u32*  cnt3  = (u32*)(ws+OFF_C3);
  u32*  histS = (u32*)(ws+OFF_HS);
  u32*  bsum  = (u32*)(ws+OFF_BS);
  u32*  pref3 = (u32*)(ws+OFF_P3);
  u32*  keys3 = (u32*)(ws+OFF_K3);
  u16*  lo3   = (u16*)(ws+OFF_L3);
  u32*  keysS = (u32*)(ws+OFF_KSC);
  int*  idxb  = (int*)(ws+OFF_IDX);
  float* rew  = (float*)(ws+OFF_REW);
  u16*  hm    = (u16*)(ws+OFF_HM);
  u16*  ht    = (u16*)(ws+OFF_HT);
  float* vecs = (float*)(ws+OFF_VECS);
  u16*  lnb   = (u16*)(ws+OFF_LNB);
  u16*  qkvb  = (u16*)(ws+OFF_QKV);
  u16*  attn  = (u16*)(ws+OFF_ATT);
  u16*  ffh   = (u16*)(ws+OFF_FFH);
  u16*  vhin  = (u16*)(ws+OFF_VHIN);
  u16*  wb    = (u16*)(ws+OFF_WB);
  u16*  part  = (u16*)(ws+OFF_PART);
  u16*  part2 = part + (size_t)8*KS*HD;

  u16* inW_bf = wb + WB_IN;
  u16* oW_bf  = wb + WB_O;
  u16* f1w_bf = wb + WB_F1;
  u16* f2w_bf = wb + WB_F2;
  u16* am_bf  = wb + WB_AM;
  u16* at_bf  = wb + WB_AT;
  u16* vh_bf  = wb + WB_VH;

  dim3 b256(256);
  int gN = NM/256;

  // ---- weight conversion + hist zeroing (one kernel) ----
  {
    WCA a;
    const float* srcs[7] = { inW, oW, f1w, f2w, amw2, atw2, vw1 };
    u16* dsts[7] = { inW_bf, oW_bf, f1w_bf, f2w_bf, am_bf, at_bf, vh_bf };
    u32 sizes4[7] = { 4*3*HD*HD/4, 4*HD*HD/4, 4*4*HD*HD/4, 4*4*HD*HD/4, HD*HD/4, HD*HD/4, 4*HD*HD/4 };
    u32 cum = 0;
    for(int j=0;j<7;++j){
      a.seg[j].s = srcs[j]; a.seg[j].d = dsts[j];
      a.seg[j].base4 = cum; cum += sizes4[j]; a.seg[j].end4 = cum;
    }
    a.tot4 = cum;
    a.z = (u32*)ws;
    hipLaunchKernelGGL(k_wconv, dim3((cum + 255)/256), b256, 0, stream, a);
  }

  // ---- scoring / ranking / top-k ----
  hipLaunchKernelGGL(k_simkey, dim3(NM/8), b256, 0, stream, mv, x, surp, noise, keys3, hist3);
  hipLaunchKernelGGL(k_scanA, dim3(192), b256, 0, stream, hist3, bsum);
  hipLaunchKernelGGL(k_scanC, dim3(192), b256, 0, stream, hist3, bsum, pref3);
  hipLaunchKernelGGL(k_scatter3, dim3(gN), b256, 0, stream, keys3, pref3, cnt3, lo3);
  hipLaunchKernelGGL(k_rank3score, dim3(gN), b256, 0, stream, keys3, pref3, lo3, keysS, histS);
  hipLaunchKernelGGL(k_selsort, dim3(1), dim3(1024), 0, stream, histS, keysS, idxb);

  // ---- gather + action MLPs + assembly/LN1 ----
  hipLaunchKernelGGL(k_gather, dim3(KS+1), b256, 0, stream, idxb, mv, mnv, mrew, aim, ait,
                     amw1, amb1, atw1, atb1, start, x, pos,
                     vecs, out + OUT_NEXT, hm, ht, rew, out + OUT_REWO);
  hipLaunchKernelGGL(k_actgemm, dim3(512), b256, 0, stream, hm, ht, am_bf, at_bf, part, part2);
  hipLaunchKernelGGL(k_finavln, dim3(SQ), b256, 0, stream, part, part2, amb2, atb2, pos, vecs, l1w, l1b, lnb);

  // ---- transformer (qkv/ffn1 S=4; o-proj/ffn2 S=8) ----
  for(int l=0;l<NL;++l){
    hipLaunchKernelGGL(k_gemm, dim3(960), b256, 0, stream, lnb, inW_bf + (size_t)l*3*HD*HD, part, SQ, 3*HD, HD, 4, 5, HD);
    hipLaunchKernelGGL((k_finS<4,0,true>), dim3(774), b256, 0, stream, part, inB + (size_t)l*3*HD, (float*)nullptr, qkvb, SQ*3*HD/4, 3*HD);
    hipLaunchKernelGGL(k_attn, dim3(SQ/2, 16), b256, 0, stream, qkvb, attn);
    hipLaunchKernelGGL(k_gemm, dim3(640), b256, 0, stream, attn, oW_bf + (size_t)l*HD*HD, part, SQ, HD, HD, 8, 5, HD);
    hipLaunchKernelGGL((k_finrow<8,true>), dim3(SQ), b256, 0, stream, part, oB + (size_t)l*HD, vecs,
                       l2w + (size_t)l*HD, l2b + (size_t)l*HD, lnb, (float*)nullptr, (u16*)nullptr);
    hipLaunchKernelGGL(k_gemm, dim3(1280), b256, 0, stream, lnb, f1w_bf + (size_t)l*4*HD*HD, part, SQ, 4*HD, HD, 4, 5, HD);
    hipLaunchKernelGGL((k_finS<4,1,true>), dim3(1032), b256, 0, stream, part, f1b + (size_t)l*4*HD, (float*)nullptr, ffh, SQ*4*HD/4, 4*HD);
    hipLaunchKernelGGL(k_gemm, dim3(640), b256, 0, stream, ffh, f2w_bf + (size_t)l*HD*4*HD, part, SQ, HD, 4*HD, 8, 5, 4*HD);
    if(l < NL-1)
      hipLaunchKernelGGL((k_finrow<8,true>), dim3(SQ), b256, 0, stream, part, f2b + (size_t)l*HD, vecs,
                         l1w + (size_t)(l+1)*HD, l1b + (size_t)(l+1)*HD, lnb, (float*)nullptr, (u16*)nullptr);
    else
      hipLaunchKernelGGL((k_finrow<8,false>), dim3(SQ), b256, 0, stream, part, f2b + (size_t)l*HD, vecs,
                         (const float*)nullptr, (const float*)nullptr, (u16*)nullptr, out, vhin);
  }

  // ---- value head: S=4, 768 blocks ----
  hipLaunchKernelGGL(k_gemm, dim3(768), b256, 0, stream, vhin, vh_bf, part, KS+1, 4*HD, HD, 4, 3, HD);
  hipLaunchKernelGGL(k_vpfin, dim3(KS+1), b256, 0, stream, part, vb1, vw2, vb2, rew, out);
}